// Round 7
// baseline (3577.082 us; speedup 1.0000x reference)
//
#include <hip/hip_runtime.h>
#include <cstdint>
#include <cstddef>

typedef unsigned short u16;
typedef short bf16x8 __attribute__((ext_vector_type(8)));
typedef u16   u16x8  __attribute__((ext_vector_type(8)));
typedef float f32x4  __attribute__((ext_vector_type(4)));

#define NT  512
#define NB  64
#define NH  1024
#define NTB 32768   // NT*NB
#define G4  4096

#define AS1C(p) ((const __attribute__((address_space(1))) void*)(p))
#define AS3(p)  ((__attribute__((address_space(3))) void*)(p))

__device__ __forceinline__ float b2f(u16 u){
  return __uint_as_float(((unsigned)u) << 16);
}
__device__ __forceinline__ u16 f2b(float f){
  unsigned u = __float_as_uint(f);
  return (u16)((u + 0x7fffu + ((u >> 16) & 1u)) >> 16);
}
__device__ __forceinline__ float fsigmoid(float x){
  return __builtin_amdgcn_rcpf(1.f + __builtin_amdgcn_exp2f(-1.442695041f * x));
}
__device__ __forceinline__ float ftanh(float x){
  return 2.f * __builtin_amdgcn_rcpf(1.f + __builtin_amdgcn_exp2f(-2.885390082f * x)) - 1.f;
}

// ---------------- f32 -> bf16 conversion ----------------
__global__ void cvt_bf16(const float* __restrict__ in, u16* __restrict__ out, int n8){
  int stride = gridDim.x * blockDim.x;
  for (int i = blockIdx.x * blockDim.x + threadIdx.x; i < n8; i += stride){
    const float4* p = (const float4*)(in + (size_t)i * 8);
    float4 a = p[0], b = p[1];
    u16x8 r;
    r[0]=f2b(a.x); r[1]=f2b(a.y); r[2]=f2b(a.z); r[3]=f2b(a.w);
    r[4]=f2b(b.x); r[5]=f2b(b.y); r[6]=f2b(b.z); r[7]=f2b(b.w);
    *(u16x8*)(out + (size_t)i * 8) = r;
  }
}

// ---------------- z-gate precompute ----------------
__global__ void zpre_kernel(const float* __restrict__ x, const float* __restrict__ Wih,
                            const float* __restrict__ b_ih, const float* __restrict__ b_hh,
                            float* __restrict__ zp){
  int gw   = (blockIdx.x * 256 + threadIdx.x) >> 6;
  int lane = threadIdx.x & 63;
  const float* wz = Wih + (size_t)4096 * 1024;
  float4 wv[4];
  #pragma unroll
  for (int j = 0; j < 4; ++j) wv[j] = *(const float4*)&wz[lane*16 + j*4];
  float bz = b_ih[4096] + b_hh[4096];
  for (int r = gw; r < NTB; r += 1024){
    const float* xr = x + (size_t)r * 1024 + lane * 16;
    float s = 0.f;
    #pragma unroll
    for (int j = 0; j < 4; ++j){
      float4 xv = *(const float4*)&xr[j*4];
      s += xv.x*wv[j].x + xv.y*wv[j].y + xv.z*wv[j].z + xv.w*wv[j].w;
    }
    #pragma unroll
    for (int o = 32; o > 0; o >>= 1) s += __shfl_down(s, o);
    if (lane == 0) zp[r] = s + bz;
  }
}

// ---------------- Phase-1 GEMM: gx[32768,4096] = Xb @ Wb^T + bias ----------------
template<typename GT>
__global__ __launch_bounds__(256, 2) void gemm_gx(
    const u16* __restrict__ Xb, const u16* __restrict__ Wb,
    const float* __restrict__ b_ih, const float* __restrict__ b_hh,
    GT* __restrict__ gx)
{
  __shared__ u16 As[128*32];
  __shared__ u16 Bs[128*32];
  const int tid  = threadIdx.x;
  const int lane = tid & 63, wave = tid >> 6;
  const int wr = wave >> 1, wc = wave & 1;
  const int m0 = (blockIdx.x & 255) * 128;
  const int n0 = (blockIdx.x >> 8) * 128;
  const int srow = wave * 16 + (lane >> 2);
  const int scol = (lane & 3) * 8;
  const u16* gA = Xb + (size_t)(m0 + srow) * 1024 + scol;
  const u16* gB = Wb + (size_t)(n0 + srow) * 1024 + scol;
  char* lA = (char*)As + wave * 1024;
  char* lB = (char*)Bs + wave * 1024;
  const int fr = lane & 15, fo = (lane >> 4) * 8;

  f32x4 acc[4][4] = {};
  for (int k0 = 0; k0 < 1024; k0 += 32){
    __syncthreads();
    __builtin_amdgcn_global_load_lds(AS1C(gA + k0),            AS3(lA),        16, 0, 0);
    __builtin_amdgcn_global_load_lds(AS1C(gA + 64*1024 + k0),  AS3(lA + 4096), 16, 0, 0);
    __builtin_amdgcn_global_load_lds(AS1C(gB + k0),            AS3(lB),        16, 0, 0);
    __builtin_amdgcn_global_load_lds(AS1C(gB + 64*1024 + k0),  AS3(lB + 4096), 16, 0, 0);
    __syncthreads();
    bf16x8 a[4], b[4];
    #pragma unroll
    for (int mi = 0; mi < 4; ++mi)
      a[mi] = *(const bf16x8*)&As[(wr*64 + mi*16 + fr)*32 + fo];
    #pragma unroll
    for (int ni = 0; ni < 4; ++ni)
      b[ni] = *(const bf16x8*)&Bs[(wc*64 + ni*16 + fr)*32 + fo];
    #pragma unroll
    for (int mi = 0; mi < 4; ++mi)
      #pragma unroll
      for (int ni = 0; ni < 4; ++ni)
        acc[mi][ni] = __builtin_amdgcn_mfma_f32_16x16x32_bf16(a[mi], b[ni], acc[mi][ni], 0, 0, 0);
  }
  const int orow = (lane >> 4) * 4, ocol = lane & 15;
  #pragma unroll
  for (int ni = 0; ni < 4; ++ni){
    const int g = n0 + wc*64 + ni*16 + ocol;
    const float bias = b_ih[g] + b_hh[g];
    #pragma unroll
    for (int mi = 0; mi < 4; ++mi){
      const size_t rb = (size_t)(m0 + wr*64 + mi*16 + orow);
      #pragma unroll
      for (int r = 0; r < 4; ++r){
        float v = acc[mi][ni][r] + bias;
        if constexpr (sizeof(GT) == 4)
          __builtin_nontemporal_store(v, (float*)gx + (rb + r)*G4 + g);
        else
          __builtin_nontemporal_store(f2b(v), (u16*)gx + (rb + r)*G4 + g);
      }
    }
  }
}

// tagged-h load: same-XCD fast path (sc0, L2) / fallback coherent path (sc0 sc1, L3)
__device__ __forceinline__ uint4 ld_h(const uint4* p, bool fb){
  uint4 r;
  if (fb) asm volatile("global_load_dwordx4 %0, %1, off sc0 sc1" : "=v"(r) : "v"(p) : "memory");
  else    asm volatile("global_load_dwordx4 %0, %1, off sc0"     : "=v"(r) : "v"(p) : "memory");
  return r;
}

// ---------------- Phase-2 persistent scan: XCD-local groups ----------------
// 8 groups x 8 batches. Group = blockIdx&7 (XCD round-robin assumption), 32 WGs
// x 512 thr; WG owns 32 gate-cols (4 gates). W_hh slice pinned in VGPRs.
// h element = dword (bf16<<16)|tag, tag = t+1, parity double-buffer.
// Publish: sc0 sc1 dword store (no ack/flag). Poll: sc0 loads (L2-speed on
// same XCD); self-correcting via tags; persistent per-WG sc1 fallback.
// RULE: every inline-asm load is drained (vmcnt) before its destination
// variable's live range ends — retry loop uses vmcnt(0) so no load escapes
// into the MFMA phase where its VGPRs get reused (the R6 bug).
template<typename GT>
__global__ __launch_bounds__(512, 2) void hmlstm_scan(
    const u16* __restrict__ Whhb, const float* __restrict__ Whhf,
    const GT* __restrict__ gx, const float* __restrict__ zpre,
    unsigned* __restrict__ hdw, float* __restrict__ out)
{
  const int tid  = threadIdx.x;
  const int lane = tid & 63, wave = tid >> 6;     // 8 waves
  const int gw = wave >> 1, cb = wave & 1;        // gate, col-half
  const int fr = lane & 15, hi4 = lane >> 4;
  const int g  = blockIdx.x & 7;                  // group == XCD (assumed)
  const int hb = blockIdx.x >> 3;                 // 0..31, 32 cols each

  __shared__ u16   hs[8*1024];        // 16KB swizzled bf16 [8][1024]
  __shared__ float wzf[1024];         // z-row weights f32
  __shared__ float glds[4][8][32];    // gate transpose
  __shared__ float zsum[8];

  for (int i = tid; i < 1024; i += 512) wzf[i] = Whhf[(size_t)4096*1024 + i];

  // persistent B fragments: gate-row = gw*1024 + hb*32 + cb*16 + fr
  const int grow = gw*1024 + hb*32 + cb*16 + fr;
  bf16x8 Bw[32];
  #pragma unroll
  for (int kc = 0; kc < 32; ++kc)
    Bw[kc] = *(const bf16x8*)&Whhb[(size_t)grow*1024 + kc*32 + hi4*8];
  #pragma unroll
  for (int kc = 0; kc < 32; ++kc)
    asm volatile("" : "+v"(Bw[kc]));

  // publish h^0 = 0 (tag 1) into parity-0
  if (tid < 256){
    int b = tid >> 5, c = tid & 31;
    unsigned* p = hdw + (size_t)(g*8 + b)*1024 + hb*32 + c;
    unsigned v0 = 1u;
    asm volatile("global_store_dword %0, %1, off sc0 sc1" :: "v"(p), "v"(v0) : "memory");
  }

  const int srow = wave;                 // stage row = batch 0..7
  const int scol = (lane) * 16;          // dword col base (64 lanes x 16)
  float c_reg = 0.f;
  bool  fb = false;

  for (int t = 0; t < NT; ++t){
    const unsigned* src = hdw + (size_t)(t & 1) * 65536;
    unsigned*       dst = hdw + (size_t)((t + 1) & 1) * 65536;
    const unsigned  tgt = (unsigned)(t + 1);
    const unsigned* rbase = src + (size_t)(g*8 + srow)*1024 + scol;

    // ---- issue h-chunk loads FIRST (oldest), then gx/zpre (stay in flight)
    uint4 v[4];
    #pragma unroll
    for (int q = 0; q < 4; ++q) v[q] = ld_h((const uint4*)(rbase + q*4), fb);

    float gxl[4]; float zpc;
    {
      const GT* gp = gx + ((size_t)t*64 + g*8 + (hi4 & 1)*4)*G4 + grow;
      if constexpr (sizeof(GT) == 4){
        #pragma unroll
        for (int r = 0; r < 4; ++r)
          asm volatile("global_load_dword %0, %1, off nt" : "=v"(gxl[r]) : "v"((const float*)gp + (size_t)r*G4) : "memory");
      } else {
        #pragma unroll
        for (int r = 0; r < 4; ++r)
          asm volatile("global_load_ushort %0, %1, off nt" : "=v"(*(unsigned*)&gxl[r]) : "v"((const u16*)gp + (size_t)r*G4) : "memory");
      }
      asm volatile("global_load_dword %0, %1, off" : "=v"(zpc) : "v"(zpre + t*64 + g*8 + ((tid>>5)&7)) : "memory");
    }
    asm volatile("s_waitcnt vmcnt(5)" ::: "memory");   // drain the 4 h chunks (oldest)
    __builtin_amdgcn_sched_barrier(0);

    // ---- validate tags; retry stale chunks.
    // Retry drains with vmcnt(0): no reissued load may outlive v[] (R6 bug fix).
    unsigned pend = 0;
    #pragma unroll
    for (int q = 0; q < 4; ++q){
      unsigned m = ((v[q].x^tgt)|(v[q].y^tgt)|(v[q].z^tgt)|(v[q].w^tgt)) & 0xFFFFu;
      pend |= (m == 0) ? 0u : (1u << q);
    }
    int spin = 0;
    while (__any((int)(pend != 0u))){
      if (++spin > 8){ fb = true; }
      fb = (bool)__any((int)fb);                       // wave-uniform
      #pragma unroll
      for (int q = 0; q < 4; ++q)
        if (__any((int)((pend >> q) & 1u)))
          v[q] = ld_h((const uint4*)(rbase + q*4), fb);
      asm volatile("s_waitcnt vmcnt(0)" ::: "memory");
      __builtin_amdgcn_sched_barrier(0);
      #pragma unroll
      for (int q = 0; q < 4; ++q){
        if ((pend >> q) & 1u){
          unsigned m = ((v[q].x^tgt)|(v[q].y^tgt)|(v[q].z^tgt)|(v[q].w^tgt)) & 0xFFFFu;
          if (m == 0) pend &= ~(1u << q);
        }
      }
    }

    // ---- strip tags -> swizzled LDS (16B-unit XOR by row)
    #pragma unroll
    for (int q = 0; q < 4; ++q){
      unsigned p0 = (v[q].x >> 16) | (v[q].y & 0xFFFF0000u);
      unsigned p1 = (v[q].z >> 16) | (v[q].w & 0xFFFF0000u);
      uint2 pw = {p0, p1};
      int u16b = lane*32 + (q >> 1)*16;                 // 16B-aligned unit
      int addr = srow*2048 + ((u16b ^ (srow << 4))) + (q & 1)*8;
      *(uint2*)((char*)hs + addr) = pw;
    }
    __syncthreads();

    // ---- recurrent GEMM: wave computes its 16 gate-cols x 8 batches, K=1024
    f32x4 acc0 = {}, acc1 = {}, acc2 = {}, acc3 = {};
    const int arow = fr & 7;
    #pragma unroll
    for (int kc = 0; kc < 32; kc += 4){
      bf16x8 a0 = *(const bf16x8*)((char*)hs + arow*2048 + (((kc+0)*64 + hi4*16) ^ (arow << 4)));
      bf16x8 a1 = *(const bf16x8*)((char*)hs + arow*2048 + (((kc+1)*64 + hi4*16) ^ (arow << 4)));
      bf16x8 a2 = *(const bf16x8*)((char*)hs + arow*2048 + (((kc+2)*64 + hi4*16) ^ (arow << 4)));
      bf16x8 a3 = *(const bf16x8*)((char*)hs + arow*2048 + (((kc+3)*64 + hi4*16) ^ (arow << 4)));
      acc0 = __builtin_amdgcn_mfma_f32_16x16x32_bf16(a0, Bw[kc+0], acc0, 0, 0, 0);
      acc1 = __builtin_amdgcn_mfma_f32_16x16x32_bf16(a1, Bw[kc+1], acc1, 0, 0, 0);
      acc2 = __builtin_amdgcn_mfma_f32_16x16x32_bf16(a2, Bw[kc+2], acc2, 0, 0, 0);
      acc3 = __builtin_amdgcn_mfma_f32_16x16x32_bf16(a3, Bw[kc+3], acc3, 0, 0, 0);
    }
    f32x4 ac = (acc0 + acc1) + (acc2 + acc3);

    // ---- z partial: wave = batch, 16 cols/lane, full-wave reduce
    {
      int bz = wave;
      float zp = 0.f;
      int b0 = bz*2048 + ((lane*32) ^ (bz << 4));
      int b1 = bz*2048 + ((lane*32 + 16) ^ (bz << 4));
      bf16x8 h0 = *(const bf16x8*)((char*)hs + b0);
      bf16x8 h1 = *(const bf16x8*)((char*)hs + b1);
      #pragma unroll
      for (int e = 0; e < 8; ++e){
        zp += b2f((u16)h0[e]) * wzf[lane*16 + e];
        zp += b2f((u16)h1[e]) * wzf[lane*16 + 8 + e];
      }
      #pragma unroll
      for (int o = 32; o > 0; o >>= 1) zp += __shfl_xor(zp, o);
      if (lane == 0) zsum[bz] = zp;
    }

    // ---- FENCE for gx/zpre inline-asm loads (rule #18)
    asm volatile("s_waitcnt vmcnt(0)" ::: "memory");
    __builtin_amdgcn_sched_barrier(0);

    if constexpr (sizeof(GT) != 4){
      #pragma unroll
      for (int r = 0; r < 4; ++r)
        gxl[r] = __uint_as_float((*(unsigned*)&gxl[r]) << 16);
    }

    // ---- gates -> LDS (batches = acc rows 0..7, lanes hi4<2)
    if (hi4 < 2){
      #pragma unroll
      for (int r = 0; r < 4; ++r){
        float vv = ac[r] + gxl[r];
        float s = (gw == 2) ? ftanh(vv) : fsigmoid(vv);
        glds[gw][hi4*4 + r][cb*16 + fr] = s;
      }
    }
    __syncthreads();

    // ---- combine + publish (tid<256): thread = (batch b, col c)
    if (tid < 256){
      int b = tid >> 5, c = tid & 31;
      float iv  = glds[0][b][c], fvg = glds[1][b][c];
      float gv  = glds[2][b][c], ov  = glds[3][b][c];
      float zv  = fsigmoid(zpc + zsum[b]);
      float ig  = iv * gv;
      float cn  = zv*ig + (1.f - zv)*(fvg*c_reg + ig);
      float hv_ = ov * ftanh(cn);
      c_reg = cn;
      const int hoff = (g*8 + b)*1024 + hb*32 + c;
      unsigned pv = ((unsigned)f2b(hv_) << 16) | (unsigned)(t + 2);
      asm volatile("global_store_dword %0, %1, off sc0 sc1" :: "v"(dst + hoff), "v"(pv) : "memory");
      __builtin_nontemporal_store(hv_, out + (size_t)t*65536 + hoff);
      if (t == NT-1){
        out[(size_t)NT*65536 + hoff] = hv_;            // hT
        out[(size_t)NT*65536 + 65536 + hoff] = cn;     // cT
      }
    }
  }
}

// ---------------- host ----------------
extern "C" void kernel_launch(void* const* d_in, const int* in_sizes, int n_in,
                              void* d_out, int out_size, void* d_ws, size_t ws_size,
                              hipStream_t stream)
{
  (void)in_sizes; (void)n_in; (void)out_size;
  const float* x    = (const float*)d_in[0];
  const float* Wih  = (const float*)d_in[1];
  const float* Whh  = (const float*)d_in[2];
  const float* b_ih = (const float*)d_in[3];
  const float* b_hh = (const float*)d_in[4];
  float* out = (float*)d_out;

  size_t off = 0;
  auto alloc = [&](size_t bytes)->void*{
    void* p = (char*)d_ws + off;
    off = (off + bytes + 255) & ~(size_t)255;
    return p;
  };
  u16*  xb    = (u16*) alloc((size_t)NTB*1024*2);
  u16*  wihb  = (u16*) alloc((size_t)4097*1024*2);
  u16*  whhb  = (u16*) alloc((size_t)4097*1024*2);
  unsigned* hdw = (unsigned*)alloc((size_t)2*65536*4);   // tagged h, 2 parities
  float* zp   = (float*)alloc((size_t)NTB*4);
  bool g32 = (ws_size >= off + (size_t)NTB*G4*4);
  void* gxp = (char*)d_ws + off;

  hipMemsetAsync(hdw, 0, (size_t)2*65536*4, stream);   // kill stale tags (replay safety)
  cvt_bf16<<<dim3(2048), dim3(256), 0, stream>>>(x,   xb,   NTB*1024/8);
  cvt_bf16<<<dim3(512),  dim3(256), 0, stream>>>(Wih, wihb, 4097*1024/8);
  cvt_bf16<<<dim3(512),  dim3(256), 0, stream>>>(Whh, whhb, 4097*1024/8);
  zpre_kernel<<<dim3(256), dim3(256), 0, stream>>>(x, Wih, b_ih, b_hh, zp);
  if (g32){
    float* gxf = (float*)gxp;
    gemm_gx<float><<<dim3(8192), dim3(256), 0, stream>>>(xb, wihb, b_ih, b_hh, gxf);
    void* args[] = { (void*)&whhb, (void*)&Whh, (void*)&gxf, (void*)&zp, (void*)&hdw, (void*)&out };
    if (hipLaunchCooperativeKernel((void*)hmlstm_scan<float>, dim3(256), dim3(512),
                                   args, 0, stream) != hipSuccess)
      hmlstm_scan<float><<<dim3(256), dim3(512), 0, stream>>>(whhb, Whh, gxf, zp, hdw, out);
  } else {
    u16* gxb = (u16*)gxp;
    gemm_gx<u16><<<dim3(8192), dim3(256), 0, stream>>>(xb, wihb, b_ih, b_hh, gxb);
    void* args[] = { (void*)&whhb, (void*)&Whh, (void*)&gxb, (void*)&zp, (void*)&hdw, (void*)&out };
    if (hipLaunchCooperativeKernel((void*)hmlstm_scan<u16>, dim3(256), dim3(512),
                                   args, 0, stream) != hipSuccess)
      hmlstm_scan<u16><<<dim3(256), dim3(512), 0, stream>>>(whhb, Whh, gxb, zp, hdw, out);
  }
}

// Round 8
// 3457.114 us; speedup vs baseline: 1.0347x; 1.0347x over previous
//
#include <hip/hip_runtime.h>
#include <cstdint>
#include <cstddef>

typedef unsigned short u16;
typedef short bf16x8 __attribute__((ext_vector_type(8)));
typedef u16   u16x8  __attribute__((ext_vector_type(8)));
typedef float f32x4  __attribute__((ext_vector_type(4)));

#define NT  512
#define NB  64
#define NH  1024
#define NTB 32768   // NT*NB
#define G4  4096

#define AS1C(p) ((const __attribute__((address_space(1))) void*)(p))
#define AS3(p)  ((__attribute__((address_space(3))) void*)(p))

__device__ __forceinline__ float b2f(u16 u){
  return __uint_as_float(((unsigned)u) << 16);
}
__device__ __forceinline__ u16 f2b(float f){
  unsigned u = __float_as_uint(f);
  return (u16)((u + 0x7fffu + ((u >> 16) & 1u)) >> 16);
}
__device__ __forceinline__ float fsigmoid(float x){
  return __builtin_amdgcn_rcpf(1.f + __builtin_amdgcn_exp2f(-1.442695041f * x));
}
__device__ __forceinline__ float ftanh(float x){
  return 2.f * __builtin_amdgcn_rcpf(1.f + __builtin_amdgcn_exp2f(-2.885390082f * x)) - 1.f;
}

// ---------------- f32 -> bf16 conversion ----------------
__global__ void cvt_bf16(const float* __restrict__ in, u16* __restrict__ out, int n8){
  int stride = gridDim.x * blockDim.x;
  for (int i = blockIdx.x * blockDim.x + threadIdx.x; i < n8; i += stride){
    const float4* p = (const float4*)(in + (size_t)i * 8);
    float4 a = p[0], b = p[1];
    u16x8 r;
    r[0]=f2b(a.x); r[1]=f2b(a.y); r[2]=f2b(a.z); r[3]=f2b(a.w);
    r[4]=f2b(b.x); r[5]=f2b(b.y); r[6]=f2b(b.z); r[7]=f2b(b.w);
    *(u16x8*)(out + (size_t)i * 8) = r;
  }
}

// ---------------- z-gate precompute ----------------
__global__ void zpre_kernel(const float* __restrict__ x, const float* __restrict__ Wih,
                            const float* __restrict__ b_ih, const float* __restrict__ b_hh,
                            float* __restrict__ zp){
  int gw   = (blockIdx.x * 256 + threadIdx.x) >> 6;
  int lane = threadIdx.x & 63;
  const float* wz = Wih + (size_t)4096 * 1024;
  float4 wv[4];
  #pragma unroll
  for (int j = 0; j < 4; ++j) wv[j] = *(const float4*)&wz[lane*16 + j*4];
  float bz = b_ih[4096] + b_hh[4096];
  for (int r = gw; r < NTB; r += 1024){
    const float* xr = x + (size_t)r * 1024 + lane * 16;
    float s = 0.f;
    #pragma unroll
    for (int j = 0; j < 4; ++j){
      float4 xv = *(const float4*)&xr[j*4];
      s += xv.x*wv[j].x + xv.y*wv[j].y + xv.z*wv[j].z + xv.w*wv[j].w;
    }
    #pragma unroll
    for (int o = 32; o > 0; o >>= 1) s += __shfl_down(s, o);
    if (lane == 0) zp[r] = s + bz;
  }
}

// ---------------- Phase-1 GEMM: gx[32768,4096] = Xb @ Wb^T + bias ----------------
template<typename GT>
__global__ __launch_bounds__(256, 2) void gemm_gx(
    const u16* __restrict__ Xb, const u16* __restrict__ Wb,
    const float* __restrict__ b_ih, const float* __restrict__ b_hh,
    GT* __restrict__ gx)
{
  __shared__ u16 As[128*32];
  __shared__ u16 Bs[128*32];
  const int tid  = threadIdx.x;
  const int lane = tid & 63, wave = tid >> 6;
  const int wr = wave >> 1, wc = wave & 1;
  const int m0 = (blockIdx.x & 255) * 128;
  const int n0 = (blockIdx.x >> 8) * 128;
  const int srow = wave * 16 + (lane >> 2);
  const int scol = (lane & 3) * 8;
  const u16* gA = Xb + (size_t)(m0 + srow) * 1024 + scol;
  const u16* gB = Wb + (size_t)(n0 + srow) * 1024 + scol;
  char* lA = (char*)As + wave * 1024;
  char* lB = (char*)Bs + wave * 1024;
  const int fr = lane & 15, fo = (lane >> 4) * 8;

  f32x4 acc[4][4] = {};
  for (int k0 = 0; k0 < 1024; k0 += 32){
    __syncthreads();
    __builtin_amdgcn_global_load_lds(AS1C(gA + k0),            AS3(lA),        16, 0, 0);
    __builtin_amdgcn_global_load_lds(AS1C(gA + 64*1024 + k0),  AS3(lA + 4096), 16, 0, 0);
    __builtin_amdgcn_global_load_lds(AS1C(gB + k0),            AS3(lB),        16, 0, 0);
    __builtin_amdgcn_global_load_lds(AS1C(gB + 64*1024 + k0),  AS3(lB + 4096), 16, 0, 0);
    __syncthreads();
    bf16x8 a[4], b[4];
    #pragma unroll
    for (int mi = 0; mi < 4; ++mi)
      a[mi] = *(const bf16x8*)&As[(wr*64 + mi*16 + fr)*32 + fo];
    #pragma unroll
    for (int ni = 0; ni < 4; ++ni)
      b[ni] = *(const bf16x8*)&Bs[(wc*64 + ni*16 + fr)*32 + fo];
    #pragma unroll
    for (int mi = 0; mi < 4; ++mi)
      #pragma unroll
      for (int ni = 0; ni < 4; ++ni)
        acc[mi][ni] = __builtin_amdgcn_mfma_f32_16x16x32_bf16(a[mi], b[ni], acc[mi][ni], 0, 0, 0);
  }
  const int orow = (lane >> 4) * 4, ocol = lane & 15;
  #pragma unroll
  for (int ni = 0; ni < 4; ++ni){
    const int g = n0 + wc*64 + ni*16 + ocol;
    const float bias = b_ih[g] + b_hh[g];
    #pragma unroll
    for (int mi = 0; mi < 4; ++mi){
      const size_t rb = (size_t)(m0 + wr*64 + mi*16 + orow);
      #pragma unroll
      for (int r = 0; r < 4; ++r){
        float v = acc[mi][ni][r] + bias;
        if constexpr (sizeof(GT) == 4)
          __builtin_nontemporal_store(v, (float*)gx + (rb + r)*G4 + g);
        else
          __builtin_nontemporal_store(f2b(v), (u16*)gx + (rb + r)*G4 + g);
      }
    }
  }
}

// tagged-h load: same-XCD fast path (sc0, L2) / fallback coherent path (sc0 sc1, L3)
__device__ __forceinline__ uint4 ld_h(const uint4* p, bool fb){
  uint4 r;
  if (fb) asm volatile("global_load_dwordx4 %0, %1, off sc0 sc1" : "=v"(r) : "v"(p) : "memory");
  else    asm volatile("global_load_dwordx4 %0, %1, off sc0"     : "=v"(r) : "v"(p) : "memory");
  return r;
}

// ---------------- Phase-2 persistent scan: XCD-local groups, W in AGPRs ----------------
// 8 groups x 8 batches. Group = blockIdx&7 (XCD round-robin), 32 WGs x 512 thr,
// 1 WG/CU. WG owns 128 gate-rows; per wave 16 rows x K=1024 = 128 AGPRs — parked
// via "+a" pin (VGPR side kept ~110, total <= 256/wave at 2 waves/SIMD).
// MFMA via inline asm with B operand in AGPR ("a" constraint).
// h element = dword (bf16<<16)|tag, parity double-buffer, sc0-poll protocol (R7).
template<typename GT>
__global__ __launch_bounds__(512, 2) void hmlstm_scan(
    const u16* __restrict__ Whhb, const GT* __restrict__ gx,
    const float* __restrict__ zpre, unsigned* __restrict__ hdw,
    float* __restrict__ out)
{
  const int tid  = threadIdx.x;
  const int lane = tid & 63, wave = tid >> 6;     // 8 waves
  const int gw = wave >> 1, cb = wave & 1;        // gate, col-half
  const int fr = lane & 15, hi4 = lane >> 4;
  const int g  = blockIdx.x & 7;                  // group == XCD (assumed)
  const int hb = blockIdx.x >> 3;                 // 0..31, 32 cols each

  __shared__ u16   hs[8*1024];        // 16KB swizzled bf16 [8][1024]
  __shared__ float glds[4][8][32];    // gate transpose
  __shared__ float zsum[8];

  // persistent B fragments -> AGPRs: gate-row = gw*1024 + hb*32 + cb*16 + fr
  const int grow = gw*1024 + hb*32 + cb*16 + fr;
  bf16x8 Bw[32];
  #pragma unroll
  for (int kc = 0; kc < 32; ++kc)
    Bw[kc] = *(const bf16x8*)&Whhb[(size_t)grow*1024 + kc*32 + hi4*8];
  #pragma unroll
  for (int kc = 0; kc < 32; ++kc)
    asm volatile("" : "+a"(Bw[kc]));   // park in AGPRs (128/lane); VGPR side stays free

  // per-lane z weights: wz[lane*16 .. +15] as 4x uint2 (16 bf16, 8 VGPRs)
  uint2 wzr[4];
  #pragma unroll
  for (int q = 0; q < 4; ++q)
    wzr[q] = *(const uint2*)&Whhb[(size_t)4096*1024 + lane*16 + q*4];

  // publish h^0 = 0 (tag 1) into parity-0
  if (tid < 256){
    int b = tid >> 5, c = tid & 31;
    unsigned* p = hdw + (size_t)(g*8 + b)*1024 + hb*32 + c;
    unsigned v0 = 1u;
    asm volatile("global_store_dword %0, %1, off sc0 sc1" :: "v"(p), "v"(v0) : "memory");
  }

  const int srow = wave;                 // stage row = batch 0..7
  const int scol = lane * 16;            // dword col base (64 lanes x 16)
  float c_reg = 0.f;
  bool  fb = false;

  for (int t = 0; t < NT; ++t){
    const unsigned* src = hdw + (size_t)(t & 1) * 65536;
    unsigned*       dst = hdw + (size_t)((t + 1) & 1) * 65536;
    const unsigned  tgt = (unsigned)(t + 1);
    const unsigned* rbase = src + (size_t)(g*8 + srow)*1024 + scol;

    // ---- issue h-chunk loads FIRST (oldest), then gx/zpre (stay in flight)
    uint4 v[4];
    #pragma unroll
    for (int q = 0; q < 4; ++q) v[q] = ld_h((const uint4*)(rbase + q*4), fb);

    float gxl[4]; float zpc;
    {
      const GT* gp = gx + ((size_t)t*64 + g*8 + (hi4 & 1)*4)*G4 + grow;
      if constexpr (sizeof(GT) == 4){
        #pragma unroll
        for (int r = 0; r < 4; ++r)
          asm volatile("global_load_dword %0, %1, off nt" : "=v"(gxl[r]) : "v"((const float*)gp + (size_t)r*G4) : "memory");
      } else {
        #pragma unroll
        for (int r = 0; r < 4; ++r)
          asm volatile("global_load_ushort %0, %1, off nt" : "=v"(*(unsigned*)&gxl[r]) : "v"((const u16*)gp + (size_t)r*G4) : "memory");
      }
      asm volatile("global_load_dword %0, %1, off" : "=v"(zpc) : "v"(zpre + t*64 + g*8 + ((tid>>5)&7)) : "memory");
    }
    asm volatile("s_waitcnt vmcnt(5)" ::: "memory");   // drain the 4 h chunks (oldest)
    __builtin_amdgcn_sched_barrier(0);

    // ---- validate tags; retry stale chunks (retry drains vmcnt(0): R6 rule)
    unsigned pend = 0;
    #pragma unroll
    for (int q = 0; q < 4; ++q){
      unsigned m = ((v[q].x^tgt)|(v[q].y^tgt)|(v[q].z^tgt)|(v[q].w^tgt)) & 0xFFFFu;
      pend |= (m == 0) ? 0u : (1u << q);
    }
    int spin = 0;
    while (__any((int)(pend != 0u))){
      if (++spin > 8){ fb = true; }
      fb = (bool)__any((int)fb);                       // wave-uniform
      #pragma unroll
      for (int q = 0; q < 4; ++q)
        if (__any((int)((pend >> q) & 1u)))
          v[q] = ld_h((const uint4*)(rbase + q*4), fb);
      asm volatile("s_waitcnt vmcnt(0)" ::: "memory");
      __builtin_amdgcn_sched_barrier(0);
      #pragma unroll
      for (int q = 0; q < 4; ++q){
        if ((pend >> q) & 1u){
          unsigned m = ((v[q].x^tgt)|(v[q].y^tgt)|(v[q].z^tgt)|(v[q].w^tgt)) & 0xFFFFu;
          if (m == 0) pend &= ~(1u << q);
        }
      }
    }

    // ---- strip tags -> swizzled LDS; fused z-gate FMA from registers
    float zp = 0.f;
    #pragma unroll
    for (int q = 0; q < 4; ++q){
      unsigned p0 = (v[q].x >> 16) | (v[q].y & 0xFFFF0000u);
      unsigned p1 = (v[q].z >> 16) | (v[q].w & 0xFFFF0000u);
      zp = fmaf(__uint_as_float(p0 << 16),         __uint_as_float(wzr[q].x << 16),         zp);
      zp = fmaf(__uint_as_float(p0 & 0xFFFF0000u), __uint_as_float(wzr[q].x & 0xFFFF0000u), zp);
      zp = fmaf(__uint_as_float(p1 << 16),         __uint_as_float(wzr[q].y << 16),         zp);
      zp = fmaf(__uint_as_float(p1 & 0xFFFF0000u), __uint_as_float(wzr[q].y & 0xFFFF0000u), zp);
      uint2 pw = {p0, p1};
      int u16b = lane*32 + (q >> 1)*16;                 // 16B-aligned unit
      int addr = srow*2048 + ((u16b ^ (srow << 4))) + (q & 1)*8;
      *(uint2*)((char*)hs + addr) = pw;
    }
    // wave srow owns batch srow's z row-sum
    #pragma unroll
    for (int o = 32; o > 0; o >>= 1) zp += __shfl_xor(zp, o);
    if (lane == 0) zsum[srow] = zp;
    __syncthreads();

    // ---- recurrent GEMM, B from AGPRs: 16 gate-cols x 8 batches, K=1024
    f32x4 acc0 = {}, acc1 = {}, acc2 = {}, acc3 = {};
    const int arow = fr & 7;
    #pragma unroll
    for (int kc = 0; kc < 32; kc += 4){
      bf16x8 a0 = *(const bf16x8*)((char*)hs + arow*2048 + (((kc+0)*64 + hi4*16) ^ (arow << 4)));
      bf16x8 a1 = *(const bf16x8*)((char*)hs + arow*2048 + (((kc+1)*64 + hi4*16) ^ (arow << 4)));
      bf16x8 a2 = *(const bf16x8*)((char*)hs + arow*2048 + (((kc+2)*64 + hi4*16) ^ (arow << 4)));
      bf16x8 a3 = *(const bf16x8*)((char*)hs + arow*2048 + (((kc+3)*64 + hi4*16) ^ (arow << 4)));
      asm volatile("v_mfma_f32_16x16x32_bf16 %0, %1, %2, %0" : "+v"(acc0) : "v"(a0), "a"(Bw[kc+0]));
      asm volatile("v_mfma_f32_16x16x32_bf16 %0, %1, %2, %0" : "+v"(acc1) : "v"(a1), "a"(Bw[kc+1]));
      asm volatile("v_mfma_f32_16x16x32_bf16 %0, %1, %2, %0" : "+v"(acc2) : "v"(a2), "a"(Bw[kc+2]));
      asm volatile("v_mfma_f32_16x16x32_bf16 %0, %1, %2, %0" : "+v"(acc3) : "v"(a3), "a"(Bw[kc+3]));
    }
    // asm MFMA is opaque to the compiler's hazard logic: pad before VALU reads
    asm volatile("s_nop 7\n\ts_nop 7\n\ts_nop 7" :::);
    f32x4 ac = (acc0 + acc1) + (acc2 + acc3);

    // ---- FENCE for gx/zpre inline-asm loads (rule #18)
    asm volatile("s_waitcnt vmcnt(0)" ::: "memory");
    __builtin_amdgcn_sched_barrier(0);

    if constexpr (sizeof(GT) != 4){
      #pragma unroll
      for (int r = 0; r < 4; ++r)
        gxl[r] = __uint_as_float((*(unsigned*)&gxl[r]) << 16);
    }

    // ---- gates -> LDS (batches = acc rows 0..7, lanes hi4<2)
    if (hi4 < 2){
      #pragma unroll
      for (int r = 0; r < 4; ++r){
        float vv = ac[r] + gxl[r];
        float s = (gw == 2) ? ftanh(vv) : fsigmoid(vv);
        glds[gw][hi4*4 + r][cb*16 + fr] = s;
      }
    }
    __syncthreads();

    // ---- combine + publish (tid<256): thread = (batch b, col c)
    if (tid < 256){
      int b = tid >> 5, c = tid & 31;
      float iv  = glds[0][b][c], fvg = glds[1][b][c];
      float gv  = glds[2][b][c], ov  = glds[3][b][c];
      float zv  = fsigmoid(zpc + zsum[b]);
      float ig  = iv * gv;
      float cn  = zv*ig + (1.f - zv)*(fvg*c_reg + ig);
      float hv_ = ov * ftanh(cn);
      c_reg = cn;
      const int hoff = (g*8 + b)*1024 + hb*32 + c;
      unsigned pv = ((unsigned)f2b(hv_) << 16) | (unsigned)(t + 2);
      asm volatile("global_store_dword %0, %1, off sc0 sc1" :: "v"(dst + hoff), "v"(pv) : "memory");
      __builtin_nontemporal_store(hv_, out + (size_t)t*65536 + hoff);
      if (t == NT-1){
        out[(size_t)NT*65536 + hoff] = hv_;            // hT
        out[(size_t)NT*65536 + 65536 + hoff] = cn;     // cT
      }
    }
  }
}

// ---------------- host ----------------
extern "C" void kernel_launch(void* const* d_in, const int* in_sizes, int n_in,
                              void* d_out, int out_size, void* d_ws, size_t ws_size,
                              hipStream_t stream)
{
  (void)in_sizes; (void)n_in; (void)out_size;
  const float* x    = (const float*)d_in[0];
  const float* Wih  = (const float*)d_in[1];
  const float* Whh  = (const float*)d_in[2];
  const float* b_ih = (const float*)d_in[3];
  const float* b_hh = (const float*)d_in[4];
  float* out = (float*)d_out;

  size_t off = 0;
  auto alloc = [&](size_t bytes)->void*{
    void* p = (char*)d_ws + off;
    off = (off + bytes + 255) & ~(size_t)255;
    return p;
  };
  u16*  xb    = (u16*) alloc((size_t)NTB*1024*2);
  u16*  wihb  = (u16*) alloc((size_t)4097*1024*2);
  u16*  whhb  = (u16*) alloc((size_t)4097*1024*2);
  unsigned* hdw = (unsigned*)alloc((size_t)2*65536*4);   // tagged h, 2 parities
  float* zp   = (float*)alloc((size_t)NTB*4);
  bool g32 = (ws_size >= off + (size_t)NTB*G4*4);
  void* gxp = (char*)d_ws + off;

  hipMemsetAsync(hdw, 0, (size_t)2*65536*4, stream);   // kill stale tags (replay safety)
  cvt_bf16<<<dim3(2048), dim3(256), 0, stream>>>(x,   xb,   NTB*1024/8);
  cvt_bf16<<<dim3(512),  dim3(256), 0, stream>>>(Wih, wihb, 4097*1024/8);
  cvt_bf16<<<dim3(512),  dim3(256), 0, stream>>>(Whh, whhb, 4097*1024/8);
  zpre_kernel<<<dim3(256), dim3(256), 0, stream>>>(x, Wih, b_ih, b_hh, zp);
  if (g32){
    float* gxf = (float*)gxp;
    gemm_gx<float><<<dim3(8192), dim3(256), 0, stream>>>(xb, wihb, b_ih, b_hh, gxf);
    void* args[] = { (void*)&whhb, (void*)&gxf, (void*)&zp, (void*)&hdw, (void*)&out };
    if (hipLaunchCooperativeKernel((void*)hmlstm_scan<float>, dim3(256), dim3(512),
                                   args, 0, stream) != hipSuccess)
      hmlstm_scan<float><<<dim3(256), dim3(512), 0, stream>>>(whhb, gxf, zp, hdw, out);
  } else {
    u16* gxb = (u16*)gxp;
    gemm_gx<u16><<<dim3(8192), dim3(256), 0, stream>>>(xb, wihb, b_ih, b_hh, gxb);
    void* args[] = { (void*)&whhb, (void*)&gxb, (void*)&zp, (void*)&hdw, (void*)&out };
    if (hipLaunchCooperativeKernel((void*)hmlstm_scan<u16>, dim3(256), dim3(512),
                                   args, 0, stream) != hipSuccess)
      hmlstm_scan<u16><<<dim3(256), dim3(512), 0, stream>>>(whhb, gxb, zp, hdw, out);
  }
}

// Round 10
// 3359.292 us; speedup vs baseline: 1.0648x; 1.0291x over previous
//
#include <hip/hip_runtime.h>
#include <cstdint>
#include <cstddef>

typedef unsigned short u16;
typedef short bf16x8 __attribute__((ext_vector_type(8)));
typedef u16   u16x8  __attribute__((ext_vector_type(8)));
typedef float f32x4  __attribute__((ext_vector_type(4)));

#define NT  512
#define NB  64
#define NH  1024
#define NTB 32768   // NT*NB
#define G4  4096

#define AS1C(p) ((const __attribute__((address_space(1))) void*)(p))
#define AS3(p)  ((__attribute__((address_space(3))) void*)(p))

__device__ __forceinline__ float b2f(u16 u){
  return __uint_as_float(((unsigned)u) << 16);
}
__device__ __forceinline__ u16 f2b(float f){
  unsigned u = __float_as_uint(f);
  return (u16)((u + 0x7fffu + ((u >> 16) & 1u)) >> 16);
}
__device__ __forceinline__ float fsigmoid(float x){
  return __builtin_amdgcn_rcpf(1.f + __builtin_amdgcn_exp2f(-1.442695041f * x));
}
__device__ __forceinline__ float ftanh(float x){
  return 2.f * __builtin_amdgcn_rcpf(1.f + __builtin_amdgcn_exp2f(-2.885390082f * x)) - 1.f;
}

// ---------------- f32 -> bf16 conversion ----------------
__global__ void cvt_bf16(const float* __restrict__ in, u16* __restrict__ out, int n8){
  int stride = gridDim.x * blockDim.x;
  for (int i = blockIdx.x * blockDim.x + threadIdx.x; i < n8; i += stride){
    const float4* p = (const float4*)(in + (size_t)i * 8);
    float4 a = p[0], b = p[1];
    u16x8 r;
    r[0]=f2b(a.x); r[1]=f2b(a.y); r[2]=f2b(a.z); r[3]=f2b(a.w);
    r[4]=f2b(b.x); r[5]=f2b(b.y); r[6]=f2b(b.z); r[7]=f2b(b.w);
    *(u16x8*)(out + (size_t)i * 8) = r;
  }
}

// ---------------- z-gate precompute ----------------
__global__ void zpre_kernel(const float* __restrict__ x, const float* __restrict__ Wih,
                            const float* __restrict__ b_ih, const float* __restrict__ b_hh,
                            float* __restrict__ zp){
  int gw   = (blockIdx.x * 256 + threadIdx.x) >> 6;
  int lane = threadIdx.x & 63;
  const float* wz = Wih + (size_t)4096 * 1024;
  float4 wv[4];
  #pragma unroll
  for (int j = 0; j < 4; ++j) wv[j] = *(const float4*)&wz[lane*16 + j*4];
  float bz = b_ih[4096] + b_hh[4096];
  for (int r = gw; r < NTB; r += 1024){
    const float* xr = x + (size_t)r * 1024 + lane * 16;
    float s = 0.f;
    #pragma unroll
    for (int j = 0; j < 4; ++j){
      float4 xv = *(const float4*)&xr[j*4];
      s += xv.x*wv[j].x + xv.y*wv[j].y + xv.z*wv[j].z + xv.w*wv[j].w;
    }
    #pragma unroll
    for (int o = 32; o > 0; o >>= 1) s += __shfl_down(s, o);
    if (lane == 0) zp[r] = s + bz;
  }
}

// ---------------- Phase-1 GEMM: gx[32768,4096] = Xb @ Wb^T + bias ----------------
template<typename GT>
__global__ __launch_bounds__(256, 2) void gemm_gx(
    const u16* __restrict__ Xb, const u16* __restrict__ Wb,
    const float* __restrict__ b_ih, const float* __restrict__ b_hh,
    GT* __restrict__ gx)
{
  __shared__ u16 As[128*32];
  __shared__ u16 Bs[128*32];
  const int tid  = threadIdx.x;
  const int lane = tid & 63, wave = tid >> 6;
  const int wr = wave >> 1, wc = wave & 1;
  const int m0 = (blockIdx.x & 255) * 128;
  const int n0 = (blockIdx.x >> 8) * 128;
  const int srow = wave * 16 + (lane >> 2);
  const int scol = (lane & 3) * 8;
  const u16* gA = Xb + (size_t)(m0 + srow) * 1024 + scol;
  const u16* gB = Wb + (size_t)(n0 + srow) * 1024 + scol;
  char* lA = (char*)As + wave * 1024;
  char* lB = (char*)Bs + wave * 1024;
  const int fr = lane & 15, fo = (lane >> 4) * 8;

  f32x4 acc[4][4] = {};
  for (int k0 = 0; k0 < 1024; k0 += 32){
    __syncthreads();
    __builtin_amdgcn_global_load_lds(AS1C(gA + k0),            AS3(lA),        16, 0, 0);
    __builtin_amdgcn_global_load_lds(AS1C(gA + 64*1024 + k0),  AS3(lA + 4096), 16, 0, 0);
    __builtin_amdgcn_global_load_lds(AS1C(gB + k0),            AS3(lB),        16, 0, 0);
    __builtin_amdgcn_global_load_lds(AS1C(gB + 64*1024 + k0),  AS3(lB + 4096), 16, 0, 0);
    __syncthreads();
    bf16x8 a[4], b[4];
    #pragma unroll
    for (int mi = 0; mi < 4; ++mi)
      a[mi] = *(const bf16x8*)&As[(wr*64 + mi*16 + fr)*32 + fo];
    #pragma unroll
    for (int ni = 0; ni < 4; ++ni)
      b[ni] = *(const bf16x8*)&Bs[(wc*64 + ni*16 + fr)*32 + fo];
    #pragma unroll
    for (int mi = 0; mi < 4; ++mi)
      #pragma unroll
      for (int ni = 0; ni < 4; ++ni)
        acc[mi][ni] = __builtin_amdgcn_mfma_f32_16x16x32_bf16(a[mi], b[ni], acc[mi][ni], 0, 0, 0);
  }
  const int orow = (lane >> 4) * 4, ocol = lane & 15;
  #pragma unroll
  for (int ni = 0; ni < 4; ++ni){
    const int g = n0 + wc*64 + ni*16 + ocol;
    const float bias = b_ih[g] + b_hh[g];
    #pragma unroll
    for (int mi = 0; mi < 4; ++mi){
      const size_t rb = (size_t)(m0 + wr*64 + mi*16 + orow);
      #pragma unroll
      for (int r = 0; r < 4; ++r){
        float v = acc[mi][ni][r] + bias;
        if constexpr (sizeof(GT) == 4)
          __builtin_nontemporal_store(v, (float*)gx + (rb + r)*G4 + g);
        else
          __builtin_nontemporal_store(f2b(v), (u16*)gx + (rb + r)*G4 + g);
      }
    }
  }
}

// tagged-h load: fast path sc0 (XCD-shared L2) / fallback sc0 sc1 (L3 mirror)
__device__ __forceinline__ uint4 ld_h(const uint4* p, bool fb){
  uint4 r;
  if (fb) asm volatile("global_load_dwordx4 %0, %1, off sc0 sc1" : "=v"(r) : "v"(p) : "memory");
  else    asm volatile("global_load_dwordx4 %0, %1, off sc0"     : "=v"(r) : "v"(p) : "memory");
  return r;
}

// ---------------- Phase-2 persistent scan ----------------
// 8 groups(=XCD assumed) x 8 batches; 32 WGs/group x 512 thr; 1 WG/CU.
// Wave = (gate gw, K-half kh): 32 gate-cols x K=512 -> B in 128 AGPRs.
// h publish: sc0 store to hdw (producer-XCD L2) + sc0 sc1 to hmir (L3 truth).
// Poll: sc0 on hdw; 32 stale spins -> sticky fb -> sc1 on hmir.
// gx/zpre pipelined one step ahead; rotation is guarded by vmcnt(3) +
// sched_barrier (drains gxn/zn, leaves publish stores in flight) — the R9 bug
// was rotating these inline-asm load dests WITHOUT a drain (rule #18).
template<typename GT>
__global__ __launch_bounds__(512, 2) void hmlstm_scan(
    const u16* __restrict__ Whhb, const GT* __restrict__ gx,
    const float* __restrict__ zpre, unsigned* __restrict__ hdw,
    unsigned* __restrict__ hmir, float* __restrict__ out)
{
  const int tid  = threadIdx.x;
  const int lane = tid & 63, wave = tid >> 6;     // 8 waves
  const int gw = wave >> 1, kh = wave & 1;        // gate, K-half
  const int fr = lane & 15, hi4 = lane >> 4;
  const int g  = blockIdx.x & 7;                  // group == XCD (assumed)
  const int hb = blockIdx.x >> 3;                 // 0..31, 32 gate-cols each

  __shared__ u16   hs[8*1024];         // 16KB swizzled bf16 [8][1024]
  __shared__ float glds[4][2][8][32];  // raw gate partials [gate][khalf][batch][col]
  __shared__ float zsum[8];

  // persistent B fragments -> AGPRs. cg=0/1: rows gw*1024 + hb*32 + cg*16 + fr,
  // k-range kh*512 .. +511.
  const int row0 = gw*1024 + hb*32 + fr;
  bf16x8 Bw0[16], Bw1[16];
  #pragma unroll
  for (int kk = 0; kk < 16; ++kk){
    Bw0[kk] = *(const bf16x8*)&Whhb[(size_t)row0*1024      + kh*512 + kk*32 + hi4*8];
    Bw1[kk] = *(const bf16x8*)&Whhb[(size_t)(row0+16)*1024 + kh*512 + kk*32 + hi4*8];
  }
  #pragma unroll
  for (int kk = 0; kk < 16; ++kk){
    asm volatile("" : "+a"(Bw0[kk]));
    asm volatile("" : "+a"(Bw1[kk]));
  }

  // per-lane z weights (cols lane*16 + q*4 .. +3)
  uint2 wzr[4];
  #pragma unroll
  for (int q = 0; q < 4; ++q)
    wzr[q] = *(const uint2*)&Whhb[(size_t)4096*1024 + lane*16 + q*4];

  // combine-thread identity (waves 0-3): (batch bq, col cq)
  const int bq = tid >> 5, cq = tid & 31;

  // publish h^0 = 0 (tag 1) into parity-0 of BOTH buffers
  if (tid < 256){
    unsigned* p  = hdw  + (size_t)(g*8 + bq)*1024 + hb*32 + cq;
    unsigned* pm = hmir + (size_t)(g*8 + bq)*1024 + hb*32 + cq;
    unsigned v0 = 1u;
    asm volatile("global_store_dword %0, %1, off sc0"     :: "v"(p),  "v"(v0) : "memory");
    asm volatile("global_store_dword %0, %1, off sc0 sc1" :: "v"(pm), "v"(v0) : "memory");
  }

  // gx/zpre prefetch pipeline (one step ahead), waves 0-3 only
  unsigned gxc[4], gxn[4]; float zc = 0.f, zn = 0.f;
  if (tid < 256){
    const GT* gp = gx + (size_t)(g*8 + bq)*G4 + hb*32 + cq;   // t=0
    #pragma unroll
    for (int q = 0; q < 4; ++q){
      if constexpr (sizeof(GT) == 4)
        asm volatile("global_load_dword %0, %1, off nt" : "=v"(gxc[q]) : "v"((const unsigned*)gp + q*1024) : "memory");
      else
        asm volatile("global_load_ushort %0, %1, off nt" : "=v"(gxc[q]) : "v"((const u16*)gp + q*1024) : "memory");
    }
    asm volatile("global_load_dword %0, %1, off" : "=v"(zc) : "v"(zpre + g*8 + bq) : "memory");
  }

  const int srow = wave;                 // staged batch row
  float c_reg = 0.f;
  bool  fb = false;

  for (int t = 0; t < NT; ++t){
    const size_t par  = (size_t)(t & 1) * 65536;
    const size_t parn = (size_t)((t + 1) & 1) * 65536;
    const unsigned  tgt = (unsigned)(t + 1);
    const size_t roff = (size_t)(g*8 + srow)*1024 + lane*16;
    const unsigned* rb_f = hdw  + par + roff;
    const unsigned* rb_m = hmir + par + roff;

    // ---- poll/stage: 4 dwordx4 per lane; vmcnt(0) cheap (gxc drained already)
    uint4 v[4];
    #pragma unroll
    for (int q = 0; q < 4; ++q) v[q] = ld_h((const uint4*)((fb ? rb_m : rb_f) + q*4), fb);
    asm volatile("s_waitcnt vmcnt(0)" ::: "memory");
    __builtin_amdgcn_sched_barrier(0);

    unsigned pend = 0;
    #pragma unroll
    for (int q = 0; q < 4; ++q){
      unsigned m = ((v[q].x^tgt)|(v[q].y^tgt)|(v[q].z^tgt)|(v[q].w^tgt)) & 0xFFFFu;
      pend |= (m == 0) ? 0u : (1u << q);
    }
    int spin = 0;
    while (__any((int)(pend != 0u))){
      if (++spin > 32){ fb = true; }
      fb = (bool)__any((int)fb);                       // wave-uniform, sticky
      #pragma unroll
      for (int q = 0; q < 4; ++q)
        if (__any((int)((pend >> q) & 1u)))
          v[q] = ld_h((const uint4*)((fb ? rb_m : rb_f) + q*4), fb);
      asm volatile("s_waitcnt vmcnt(0)" ::: "memory");
      __builtin_amdgcn_sched_barrier(0);
      #pragma unroll
      for (int q = 0; q < 4; ++q){
        if ((pend >> q) & 1u){
          unsigned m = ((v[q].x^tgt)|(v[q].y^tgt)|(v[q].z^tgt)|(v[q].w^tgt)) & 0xFFFFu;
          if (m == 0) pend &= ~(1u << q);
        }
      }
    }

    // ---- strip tags -> swizzled LDS (2x b128/lane); fused z FMA from regs
    float zp = 0.f;
    uint4 w0, w1;
    {
      unsigned a0 = (v[0].x >> 16) | (v[0].y & 0xFFFF0000u);
      unsigned a1 = (v[0].z >> 16) | (v[0].w & 0xFFFF0000u);
      unsigned a2 = (v[1].x >> 16) | (v[1].y & 0xFFFF0000u);
      unsigned a3 = (v[1].z >> 16) | (v[1].w & 0xFFFF0000u);
      unsigned a4 = (v[2].x >> 16) | (v[2].y & 0xFFFF0000u);
      unsigned a5 = (v[2].z >> 16) | (v[2].w & 0xFFFF0000u);
      unsigned a6 = (v[3].x >> 16) | (v[3].y & 0xFFFF0000u);
      unsigned a7 = (v[3].z >> 16) | (v[3].w & 0xFFFF0000u);
      zp = fmaf(__uint_as_float(a0 << 16),         __uint_as_float(wzr[0].x << 16),         zp);
      zp = fmaf(__uint_as_float(a0 & 0xFFFF0000u), __uint_as_float(wzr[0].x & 0xFFFF0000u), zp);
      zp = fmaf(__uint_as_float(a1 << 16),         __uint_as_float(wzr[0].y << 16),         zp);
      zp = fmaf(__uint_as_float(a1 & 0xFFFF0000u), __uint_as_float(wzr[0].y & 0xFFFF0000u), zp);
      zp = fmaf(__uint_as_float(a2 << 16),         __uint_as_float(wzr[1].x << 16),         zp);
      zp = fmaf(__uint_as_float(a2 & 0xFFFF0000u), __uint_as_float(wzr[1].x & 0xFFFF0000u), zp);
      zp = fmaf(__uint_as_float(a3 << 16),         __uint_as_float(wzr[1].y << 16),         zp);
      zp = fmaf(__uint_as_float(a3 & 0xFFFF0000u), __uint_as_float(wzr[1].y & 0xFFFF0000u), zp);
      zp = fmaf(__uint_as_float(a4 << 16),         __uint_as_float(wzr[2].x << 16),         zp);
      zp = fmaf(__uint_as_float(a4 & 0xFFFF0000u), __uint_as_float(wzr[2].x & 0xFFFF0000u), zp);
      zp = fmaf(__uint_as_float(a5 << 16),         __uint_as_float(wzr[2].y << 16),         zp);
      zp = fmaf(__uint_as_float(a5 & 0xFFFF0000u), __uint_as_float(wzr[2].y & 0xFFFF0000u), zp);
      zp = fmaf(__uint_as_float(a6 << 16),         __uint_as_float(wzr[3].x << 16),         zp);
      zp = fmaf(__uint_as_float(a6 & 0xFFFF0000u), __uint_as_float(wzr[3].x & 0xFFFF0000u), zp);
      zp = fmaf(__uint_as_float(a7 << 16),         __uint_as_float(wzr[3].y << 16),         zp);
      zp = fmaf(__uint_as_float(a7 & 0xFFFF0000u), __uint_as_float(wzr[3].y & 0xFFFF0000u), zp);
      w0 = (uint4){a0, a1, a2, a3};
      w1 = (uint4){a4, a5, a6, a7};
    }
    {
      int u0 = lane*32;                               // bf16-byte unit base
      *(uint4*)((char*)hs + srow*2048 + (u0        ^ (srow << 4))) = w0;
      *(uint4*)((char*)hs + srow*2048 + ((u0 + 16) ^ (srow << 4))) = w1;
    }
    #pragma unroll
    for (int o = 32; o > 0; o >>= 1) zp += __shfl_xor(zp, o);
    if (lane == 0) zsum[srow] = zp;

    // ---- prefetch gx/zpre for t+1 (off critical path; retires during compute)
    if (tid < 256){
      int tc = (t + 1 < NT) ? (t + 1) : t;
      const GT* gp = gx + ((size_t)tc*64 + g*8 + bq)*G4 + hb*32 + cq;
      #pragma unroll
      for (int q = 0; q < 4; ++q){
        if constexpr (sizeof(GT) == 4)
          asm volatile("global_load_dword %0, %1, off nt" : "=v"(gxn[q]) : "v"((const unsigned*)gp + q*1024) : "memory");
        else
          asm volatile("global_load_ushort %0, %1, off nt" : "=v"(gxn[q]) : "v"((const u16*)gp + q*1024) : "memory");
      }
      asm volatile("global_load_dword %0, %1, off" : "=v"(zn) : "v"(zpre + tc*64 + g*8 + bq) : "memory");
    }
    __syncthreads();

    // ---- recurrent GEMM: 2 col-groups x K=512 per wave, A reused across cg
    f32x4 acc00 = {}, acc01 = {}, acc10 = {}, acc11 = {};
    const int arow = fr & 7;
    const int kb2  = kh * 1024;                       // byte offset of K-half
    #pragma unroll
    for (int kk = 0; kk < 16; kk += 2){
      bf16x8 a0 = *(const bf16x8*)((char*)hs + arow*2048 + ((kb2 + (kk+0)*64 + hi4*16) ^ (arow << 4)));
      bf16x8 a1 = *(const bf16x8*)((char*)hs + arow*2048 + ((kb2 + (kk+1)*64 + hi4*16) ^ (arow << 4)));
      asm volatile("v_mfma_f32_16x16x32_bf16 %0, %1, %2, %0" : "+v"(acc00) : "v"(a0), "a"(Bw0[kk+0]));
      asm volatile("v_mfma_f32_16x16x32_bf16 %0, %1, %2, %0" : "+v"(acc10) : "v"(a0), "a"(Bw1[kk+0]));
      asm volatile("v_mfma_f32_16x16x32_bf16 %0, %1, %2, %0" : "+v"(acc01) : "v"(a1), "a"(Bw0[kk+1]));
      asm volatile("v_mfma_f32_16x16x32_bf16 %0, %1, %2, %0" : "+v"(acc11) : "v"(a1), "a"(Bw1[kk+1]));
    }
    asm volatile("s_nop 7\n\ts_nop 7\n\ts_nop 7" :::);
    f32x4 ac0 = acc00 + acc01;
    f32x4 ac1 = acc10 + acc11;

    // ---- raw partials -> LDS (rows 0..7 live in hi4<2)
    if (hi4 < 2){
      #pragma unroll
      for (int r = 0; r < 4; ++r){
        glds[gw][kh][hi4*4 + r][fr]      = ac0[r];
        glds[gw][kh][hi4*4 + r][16 + fr] = ac1[r];
      }
    }
    __syncthreads();

    // ---- combine + activation + publish (waves 0-3): thread = (bq, cq)
    if (tid < 256){
      float gi = glds[0][0][bq][cq] + glds[0][1][bq][cq];
      float gf = glds[1][0][bq][cq] + glds[1][1][bq][cq];
      float gg = glds[2][0][bq][cq] + glds[2][1][bq][cq];
      float go = glds[3][0][bq][cq] + glds[3][1][bq][cq];
      float x0, x1, x2, x3;
      if constexpr (sizeof(GT) == 4){
        x0 = __uint_as_float(gxc[0]); x1 = __uint_as_float(gxc[1]);
        x2 = __uint_as_float(gxc[2]); x3 = __uint_as_float(gxc[3]);
      } else {
        x0 = __uint_as_float(gxc[0] << 16); x1 = __uint_as_float(gxc[1] << 16);
        x2 = __uint_as_float(gxc[2] << 16); x3 = __uint_as_float(gxc[3] << 16);
      }
      float iv  = fsigmoid(gi + x0);
      float fvg = fsigmoid(gf + x1);
      float gv  = ftanh  (gg + x2);
      float ov  = fsigmoid(go + x3);
      float zv  = fsigmoid(zc + zsum[bq]);
      float ig  = iv * gv;
      float cn  = zv*ig + (1.f - zv)*(fvg*c_reg + ig);
      float hv_ = ov * ftanh(cn);
      c_reg = cn;
      const size_t hoff = (size_t)(g*8 + bq)*1024 + hb*32 + cq;
      unsigned pv = ((unsigned)f2b(hv_) << 16) | (unsigned)(t + 2);
      asm volatile("global_store_dword %0, %1, off sc0"     :: "v"(hdw  + parn + hoff), "v"(pv) : "memory");
      asm volatile("global_store_dword %0, %1, off sc0 sc1" :: "v"(hmir + parn + hoff), "v"(pv) : "memory");
      __builtin_nontemporal_store(hv_, out + (size_t)t*65536 + hoff);
      if (t == NT-1){
        out[(size_t)NT*65536 + hoff] = hv_;            // hT
        out[(size_t)NT*65536 + 65536 + hoff] = cn;     // cT
      }
    }

    // ---- drain gxn/zn BEFORE rotation (R9 bug fix; rule #18).
    // Queue (waves 0-3, oldest->newest): gxn[0..3], zn, hdw-st, hmir-st, out-st
    // -> vmcnt(3) drains loads, leaves the 3 stores fire-and-forget.
    // Waves 4-7 have nothing outstanding: no wait.
    asm volatile("s_waitcnt vmcnt(3)" ::: "memory");
    __builtin_amdgcn_sched_barrier(0);
    gxc[0]=gxn[0]; gxc[1]=gxn[1]; gxc[2]=gxn[2]; gxc[3]=gxn[3]; zc = zn;
  }
}

// ---------------- host ----------------
extern "C" void kernel_launch(void* const* d_in, const int* in_sizes, int n_in,
                              void* d_out, int out_size, void* d_ws, size_t ws_size,
                              hipStream_t stream)
{
  (void)in_sizes; (void)n_in; (void)out_size;
  const float* x    = (const float*)d_in[0];
  const float* Wih  = (const float*)d_in[1];
  const float* Whh  = (const float*)d_in[2];
  const float* b_ih = (const float*)d_in[3];
  const float* b_hh = (const float*)d_in[4];
  float* out = (float*)d_out;

  size_t off = 0;
  auto alloc = [&](size_t bytes)->void*{
    void* p = (char*)d_ws + off;
    off = (off + bytes + 255) & ~(size_t)255;
    return p;
  };
  u16*  xb    = (u16*) alloc((size_t)NTB*1024*2);
  u16*  wihb  = (u16*) alloc((size_t)4097*1024*2);
  u16*  whhb  = (u16*) alloc((size_t)4097*1024*2);
  unsigned* hdw  = (unsigned*)alloc((size_t)2*65536*4);   // tagged h (L2 fast path)
  unsigned* hmir = (unsigned*)alloc((size_t)2*65536*4);   // tagged h mirror (L3 truth)
  float* zp   = (float*)alloc((size_t)NTB*4);
  bool g32 = (ws_size >= off + (size_t)NTB*G4*4);
  void* gxp = (char*)d_ws + off;

  hipMemsetAsync(hdw, 0, (size_t)4*65536*4, stream);   // hdw+hmir (replay safety)
  cvt_bf16<<<dim3(2048), dim3(256), 0, stream>>>(x,   xb,   NTB*1024/8);
  cvt_bf16<<<dim3(512),  dim3(256), 0, stream>>>(Wih, wihb, 4097*1024/8);
  cvt_bf16<<<dim3(512),  dim3(256), 0, stream>>>(Whh, whhb, 4097*1024/8);
  zpre_kernel<<<dim3(256), dim3(256), 0, stream>>>(x, Wih, b_ih, b_hh, zp);
  if (g32){
    float* gxf = (float*)gxp;
    gemm_gx<float><<<dim3(8192), dim3(256), 0, stream>>>(xb, wihb, b_ih, b_hh, gxf);
    void* args[] = { (void*)&whhb, (void*)&gxf, (void*)&zp, (void*)&hdw, (void*)&hmir, (void*)&out };
    if (hipLaunchCooperativeKernel((void*)hmlstm_scan<float>, dim3(256), dim3(512),
                                   args, 0, stream) != hipSuccess)
      hmlstm_scan<float><<<dim3(256), dim3(512), 0, stream>>>(whhb, gxf, zp, hdw, hmir, out);
  } else {
    u16* gxb = (u16*)gxp;
    gemm_gx<u16><<<dim3(8192), dim3(256), 0, stream>>>(xb, wihb, b_ih, b_hh, gxb);
    void* args[] = { (void*)&whhb, (void*)&gxb, (void*)&zp, (void*)&hdw, (void*)&hmir, (void*)&out };
    if (hipLaunchCooperativeKernel((void*)hmlstm_scan<u16>, dim3(256), dim3(512),
                                   args, 0, stream) != hipSuccess)
      hmlstm_scan<u16><<<dim3(256), dim3(512), 0, stream>>>(whhb, gxb, zp, hdw, hmir, out);
  }
}